// Round 7
// baseline (326.516 us; speedup 1.0000x reference)
//
#include <hip/hip_runtime.h>

// entmax-1.5 over rows of an 8192 x 4096 fp32 matrix, boolean mask (int32).
// R15: ONE WAVE = ONE ROW, row DMA'd to LDS via global_load_lds, solve runs
// directly on the LDS-resident row. No ballots, no candidates, no fallback.
//
// Why (R10/R11/R14 counter-proven): hipcc will NOT keep deep global-load
// staging in VGPRs -- three different source structures all got clamped to
// <=2 chunks in flight (VGPR_Count 40 vs required ~72). Every round obeyed
// dur = bytes/BW; traffic is already minimal (131GB read-once); achieved BW
// (2.2-2.4 TB/s) is the only lever. global_load_lds is the one load path the
// allocator can't touch: fire-and-forget DMA, zero VGPR cost, MLP depth =
// number of issued instructions. 32 x 1KB DMAs issue back-to-back with
// NOTHING between them (R12 proved pure streaming runs fastest), then the
// whole pipeline (convert, max, solve, epilogue) runs out of LDS at 69TB/s.
//
// Occupancy is LDS-bound BY DESIGN: 32KB/block -> 5 blocks/CU = 1280
// resident waves; in-flight ~0.7 x 1280 x 16KB ~= 14MB >> ~2.4MB (BW x
// latency) needed to saturate HBM. Total compute ~20us of SIMD time hides
// under the ~65us BW floor via inter-block stagger.
//
// At 1.25 waves/SIMD, cross-lane latency is naked -- reductions use DPP
// (all-VALU, ~8cy/level; R9-proven correct) instead of ds_bpermute shuffles
// (~120cy/level). Solve math: exact piecewise-quadratic on the full row
// (elements with z <= mx-1 <= t contribute d=0 -- identical to the proven
// candidate solve, but with no cap and no overflow path; all-masked rows
// converge in 2 iterations through the same code).

constexpr int NROWS  = 8192;
constexpr int NCOL   = 4096;
constexpr int NCHUNK = 16;    // 16 chunks x 256 floats (64 lanes x float4)
constexpr int MAXIT  = 8;     // exact-quadratic solve cap (2-4 typical)

typedef __attribute__((address_space(1))) const void gconst_t;
typedef __attribute__((address_space(3))) void       ldsv_t;

// ---- DPP wave reductions (gfx9 canonical; all-VALU, no DS pipe) ----------
// update_dpp: lanes masked out by row/bank mask, or with no valid source
// (bound_ctrl=false), receive `oldv`. For sum: oldv=0 is the identity.
// For max: oldv=x makes masked lanes a no-op under fmax.
template <int CTRL, int RMASK, int BMASK, bool BOUND>
static __device__ __forceinline__ float dpp_f32(float oldv, float src) {
    return __int_as_float(__builtin_amdgcn_update_dpp(
        __float_as_int(oldv), __float_as_int(src), CTRL, RMASK, BMASK, BOUND));
}

// Wave-wide sum; result returned uniform (readlane 63 -> SGPR).
static __device__ __forceinline__ float wave_sum(float x) {
    x += dpp_f32<0x111, 0xf, 0xf, true>(0.f, x);   // row_shr:1
    x += dpp_f32<0x112, 0xf, 0xf, true>(0.f, x);   // row_shr:2
    x += dpp_f32<0x114, 0xf, 0xe, true>(0.f, x);   // row_shr:4
    x += dpp_f32<0x118, 0xf, 0xc, true>(0.f, x);   // row_shr:8
    x += dpp_f32<0x142, 0xa, 0xf, true>(0.f, x);   // row_bcast:15 -> rows 1,3
    x += dpp_f32<0x143, 0xc, 0xf, true>(0.f, x);   // row_bcast:31 -> rows 2,3
    return __int_as_float(__builtin_amdgcn_readlane(__float_as_int(x), 63));
}

// Wave-wide max; result returned uniform (readlane 63 -> SGPR).
static __device__ __forceinline__ float wave_max(float x) {
    x = fmaxf(x, dpp_f32<0x111, 0xf, 0xf, false>(x, x));
    x = fmaxf(x, dpp_f32<0x112, 0xf, 0xf, false>(x, x));
    x = fmaxf(x, dpp_f32<0x114, 0xf, 0xf, false>(x, x));
    x = fmaxf(x, dpp_f32<0x118, 0xf, 0xf, false>(x, x));
    x = fmaxf(x, dpp_f32<0x142, 0xa, 0xf, false>(x, x));
    x = fmaxf(x, dpp_f32<0x143, 0xc, 0xf, false>(x, x));
    return __int_as_float(__builtin_amdgcn_readlane(__float_as_int(x), 63));
}

__global__ __launch_bounds__(64)
void entmax15_kernel(const float* __restrict__ scores,
                     const int*   __restrict__ mask,
                     float*       __restrict__ out)
{
    __shared__ float sbuf[NCOL];   // scores on arrival; z after conversion
    __shared__ int   mbuf[NCOL];   // mask (dead after conversion)

    const int lane = threadIdx.x;          // block = exactly one wave
    const int row  = blockIdx.x;

    const float* srow = scores + (size_t)row * NCOL;
    const int*   mrow = mask   + (size_t)row * NCOL;
    float*       orow = out    + (size_t)row * NCOL;

    // ---- DMA the whole row into LDS: 32 back-to-back 1KB transfers.
    // Dest is wave-uniform base + lane*16 (linear, the supported pattern);
    // source is per-lane (lane's own 16B). Zero VGPR staging; the compiler
    // cannot sink or shrink these. ----
    #pragma unroll
    for (int c = 0; c < NCHUNK; ++c) {
        __builtin_amdgcn_global_load_lds(
            (gconst_t*)(srow + c * 256 + lane * 4),
            (ldsv_t*)(sbuf + c * 256), 16, 0, 0);
        __builtin_amdgcn_global_load_lds(
            (gconst_t*)(mrow + c * 256 + lane * 4),
            (ldsv_t*)(mbuf + c * 256), 16, 0, 0);
    }
    asm volatile("s_waitcnt vmcnt(0)" ::: "memory");
    __builtin_amdgcn_sched_barrier(0);     // nothing drifts above the wait

    float4* sb4 = reinterpret_cast<float4*>(sbuf);
    int4*   mb4 = reinterpret_cast<int4*>(mbuf);

    // ---- convert in place (z = mask ? s/2 : -5000 overwrites sbuf) and
    // accumulate the row max. Each lane touches exactly the 16B it DMA'd
    // per chunk: contiguous stride-16B LDS = sequential, conflict-free. ----
    float ml = -1e30f;
    #pragma unroll
    for (int c = 0; c < NCHUNK; ++c) {
        const float4 s4 = sb4[c * 64 + lane];
        const int4   m4 = mb4[c * 64 + lane];
        float4 z4;
        z4.x = m4.x ? s4.x * 0.5f : -5000.0f;
        z4.y = m4.y ? s4.y * 0.5f : -5000.0f;
        z4.z = m4.z ? s4.z * 0.5f : -5000.0f;
        z4.w = m4.w ? s4.w * 0.5f : -5000.0f;
        sb4[c * 64 + lane] = z4;
        ml = fmaxf(ml, fmaxf(fmaxf(z4.x, z4.y), fmaxf(z4.z, z4.w)));
    }
    const float mx = wave_max(ml);
    float t = mx - 1.0f;               // left bracket: tau* >= mx-1 always

    // ---- exact piecewise-quadratic solve on the full LDS row. On the
    // support at t: s0 u^2 - 2 s1 u + (s2-1) = 0; u = (s1-sqrt(disc))/s0
    // (smaller root); disc<0 -> vertex jump; overshoot self-corrects (u<0).
    // Elements below the bracket contribute d=0; no cap, no fallback.
    // All-masked rows (z==-5000 uniform) converge in 2 iters. ----
    #pragma unroll 1
    for (int itr = 0; itr < MAXIT; ++itr) {
        float s0 = 0.f, s1 = 0.f, s2 = 0.f;
        #pragma unroll
        for (int c = 0; c < NCHUNK; ++c) {
            const float4 z4 = sb4[c * 64 + lane];
            float d;
            d = fmaxf(z4.x - t, 0.f); s2 = fmaf(d, d, s2); s1 += d; s0 += (d > 0.f) ? 1.f : 0.f;
            d = fmaxf(z4.y - t, 0.f); s2 = fmaf(d, d, s2); s1 += d; s0 += (d > 0.f) ? 1.f : 0.f;
            d = fmaxf(z4.z - t, 0.f); s2 = fmaf(d, d, s2); s1 += d; s0 += (d > 0.f) ? 1.f : 0.f;
            d = fmaxf(z4.w - t, 0.f); s2 = fmaf(d, d, s2); s1 += d; s0 += (d > 0.f) ? 1.f : 0.f;
        }
        s0 = wave_sum(s0);
        s1 = wave_sum(s1);
        s2 = wave_sum(s2);
        const float s0c  = fmaxf(s0, 1.0f);     // s0>=1 at t<=tau*<mx
        const float disc = fmaf(s1, s1, -s0c * (s2 - 1.0f));
        const float u    = (s1 - sqrtf(fmaxf(disc, 0.f))) / s0c;
        t += u;                                  // wave-uniform (SGPR)
        if (__builtin_fabsf(u) < 5e-7f) break;   // wave-uniform break
    }

    // ---- epilogue: p = relu(z - tau)^2 from LDS, coalesced f4 stores ----
    #pragma unroll
    for (int c = 0; c < NCHUNK; ++c) {
        const float4 z4 = sb4[c * 64 + lane];
        float4 o;
        float d;
        d = fmaxf(z4.x - t, 0.f); o.x = d * d;
        d = fmaxf(z4.y - t, 0.f); o.y = d * d;
        d = fmaxf(z4.z - t, 0.f); o.z = d * d;
        d = fmaxf(z4.w - t, 0.f); o.w = d * d;
        *reinterpret_cast<float4*>(orow + c * 256 + lane * 4) = o;
    }
}

extern "C" void kernel_launch(void* const* d_in, const int* in_sizes, int n_in,
                              void* d_out, int out_size, void* d_ws, size_t ws_size,
                              hipStream_t stream)
{
    const float* scores = (const float*)d_in[0];
    const int*   mask   = (const int*)d_in[1];
    float*       out    = (float*)d_out;

    dim3 grid(NROWS);    // one 1-wave block per row
    dim3 block(64);
    hipLaunchKernelGGL(entmax15_kernel, grid, block, 0, stream,
                       scores, mask, out);
}